// Round 1
// baseline (434.475 us; speedup 1.0000x reference)
//
#include <hip/hip_runtime.h>

// Fused: h = relu(x @ fc1_w.T + b); TT exp-machine contraction; fc2.
// B=16384, D_IN=4096, D=10, R=2, C=10.
//
// Mapping: block = 32 rows x 8 K-chunks (chunk=512 floats).
//   thread t: lrow = t & 31, chunk = t >> 5.
//   Within a wave, lanes 0-31 share one chunk, lanes 32-63 the next ->
//   w[j][k] index is uniform per half-wave -> broadcast loads, w traffic ~41 MB
//   total instead of 2.68 GB. x is streamed per-lane (row-major, each 64B line
//   consumed by exactly one lane over 4 consecutive float4 iterations).

#define NROWS   32
#define KSPLIT  8
#define CHUNK   512    // 4096 / KSPLIT
#define DIN     4096

__global__ __launch_bounds__(256) void fused_linexp_kernel(
    const float* __restrict__ x,           // [16384, 4096]
    const float* __restrict__ fc1_w,       // [10, 4096]
    const float* __restrict__ fc1_b,       // [10]
    const float* __restrict__ core_first,  // [1, 2, 2]  -> cf[m*2 + r]
    const float* __restrict__ cores_mid,   // [8, 2, 2, 2] -> cm[k*8 + r*4 + m*2 + r']
    const float* __restrict__ core_last,   // [2, 2, 10] -> cl[(r*2+m)*10 + c]
    const float* __restrict__ fc2_w,       // [10, 10]
    const float* __restrict__ fc2_b,       // [10]
    float* __restrict__ out)               // [16384, 10]
{
    __shared__ float lds_acc[KSPLIT][NROWS][10];
    __shared__ float lds_h[NROWS][10];

    const int t     = threadIdx.x;
    const int lrow  = t & (NROWS - 1);
    const int chunk = t >> 5;
    const int grow  = blockIdx.x * NROWS + lrow;

    const float* xp = x + (size_t)grow * DIN + chunk * CHUNK;
    const float* wp = fc1_w + chunk * CHUNK;

    float acc[10];
#pragma unroll
    for (int j = 0; j < 10; ++j) acc[j] = 0.0f;

    // 128 float4 iterations per thread; unroll 4 so each j touches exactly one
    // 64B w-line per macro-iteration and 4 x-loads are in flight.
#pragma unroll 4
    for (int i = 0; i < CHUNK / 4; ++i) {
        const float4 xv = *reinterpret_cast<const float4*>(xp + i * 4);
#pragma unroll
        for (int j = 0; j < 10; ++j) {
            const float4 wv = *reinterpret_cast<const float4*>(wp + (size_t)j * DIN + i * 4);
            float a = acc[j];
            a = fmaf(xv.x, wv.x, a);
            a = fmaf(xv.y, wv.y, a);
            a = fmaf(xv.z, wv.z, a);
            a = fmaf(xv.w, wv.w, a);
            acc[j] = a;
        }
    }

#pragma unroll
    for (int j = 0; j < 10; ++j) lds_acc[chunk][lrow][j] = acc[j];
    __syncthreads();

    // 8-way chunk reduction + bias + relu: 320 (row,j) items on 256 threads.
    for (int idx = t; idx < NROWS * 10; idx += 256) {
        const int row = idx / 10;
        const int j   = idx - row * 10;
        float s = 0.0f;
#pragma unroll
        for (int c = 0; c < KSPLIT; ++c) s += lds_acc[c][row][j];
        s += fc1_b[j];
        lds_h[row][j] = s > 0.0f ? s : 0.0f;
    }
    __syncthreads();

    // Epilogue: one thread per row runs the TT chain + fc2 (~120 FLOP).
    if (t < NROWS) {
        float h[10];
#pragma unroll
        for (int j = 0; j < 10; ++j) h[j] = lds_h[t][j];

        // v = cf[0,:] + h0 * cf[1,:]   (cf[m*2 + r])
        float v0 = core_first[0] + h[0] * core_first[2];
        float v1 = core_first[1] + h[0] * core_first[3];

#pragma unroll
        for (int k = 0; k < 8; ++k) {
            const float* M = cores_mid + k * 8;  // M[r*4 + m*2 + r']
            const float hk = h[k + 1];
            const float n0 = fmaf(hk, fmaf(v0, M[2], v1 * M[6]), fmaf(v0, M[0], v1 * M[4]));
            const float n1 = fmaf(hk, fmaf(v0, M[3], v1 * M[7]), fmaf(v0, M[1], v1 * M[5]));
            v0 = n0; v1 = n1;
        }

        float vc[10];
#pragma unroll
        for (int c = 0; c < 10; ++c) {
            // cl[(r*2+m)*10 + c]
            vc[c] = fmaf(h[9], fmaf(v0, core_last[10 + c], v1 * core_last[30 + c]),
                         fmaf(v0, core_last[c], v1 * core_last[20 + c]));
        }

        float* op = out + (size_t)(blockIdx.x * NROWS + t) * 10;
#pragma unroll
        for (int n = 0; n < 10; ++n) {
            float o = fc2_b[n];
#pragma unroll
            for (int c = 0; c < 10; ++c) o = fmaf(vc[c], fc2_w[n * 10 + c], o);
            op[n] = o;
        }
    }
}

extern "C" void kernel_launch(void* const* d_in, const int* in_sizes, int n_in,
                              void* d_out, int out_size, void* d_ws, size_t ws_size,
                              hipStream_t stream) {
    const float* x          = (const float*)d_in[0];
    const float* fc1_w      = (const float*)d_in[1];
    const float* fc1_b      = (const float*)d_in[2];
    const float* core_first = (const float*)d_in[3];
    const float* cores_mid  = (const float*)d_in[4];
    const float* core_last  = (const float*)d_in[5];
    const float* fc2_w      = (const float*)d_in[6];
    const float* fc2_b      = (const float*)d_in[7];
    float* out = (float*)d_out;

    dim3 grid(16384 / NROWS);  // 512 blocks, 2 per CU
    dim3 block(256);
    fused_linexp_kernel<<<grid, block, 0, stream>>>(
        x, fc1_w, fc1_b, core_first, cores_mid, core_last, fc2_w, fc2_b, out);
}